// Round 5
// baseline (424.151 us; speedup 1.0000x reference)
//
#include <hip/hip_runtime.h>
#include <hip/hip_bf16.h>

typedef unsigned short u16;
typedef unsigned int u32;
typedef __attribute__((ext_vector_type(8))) short short8;
typedef __attribute__((ext_vector_type(4))) float f32x4;

#define MM 4096
#define NN 4096
#define KK 4096

#define BAR __builtin_amdgcn_s_barrier()
#define FENCE asm volatile("" ::: "memory")
#define WAITVM(n) asm volatile("s_waitcnt vmcnt(" #n ")" ::: "memory")

// LDS layout: Ab0 @0, Bb0 @16384, Ab1 @32768, Bb1 @49152 (u16 elements)
#define ABUF(sh, b) ((sh) + (b) * 32768)
#define BBUF(sh, b) ((sh) + 16384 + (b) * 32768)

__device__ __forceinline__ u16 f2bf(float f) {
  union { float f; u32 u; } v; v.f = f;
  u32 r = v.u + 0x7fffu + ((v.u >> 16) & 1u);
  return (u16)(r >> 16);
}

// ---- conversion passes (linear, r3 version) --------------------------------
__global__ __launch_bounds__(256) void cvt_w_k(const int* __restrict__ w,
                                               u16* __restrict__ o) {
  int i = blockIdx.x * 256 + threadIdx.x;
  const int4* w4 = (const int4*)w;
  int4 a = w4[2 * i];
  int4 b = w4[2 * i + 1];
  short8 r;
  r[0] = (short)f2bf((float)a.x); r[1] = (short)f2bf((float)a.y);
  r[2] = (short)f2bf((float)a.z); r[3] = (short)f2bf((float)a.w);
  r[4] = (short)f2bf((float)b.x); r[5] = (short)f2bf((float)b.y);
  r[6] = (short)f2bf((float)b.z); r[7] = (short)f2bf((float)b.w);
  *(short8*)(o + (size_t)i * 8) = r;
}

__global__ __launch_bounds__(256) void cvt_a_k(const float* __restrict__ x,
                                               u16* __restrict__ o) {
  int i = blockIdx.x * 256 + threadIdx.x;
  const float4* x4 = (const float4*)x;
  float4 a = x4[2 * i];
  float4 b = x4[2 * i + 1];
  short8 r;
  r[0] = (short)f2bf(a.x); r[1] = (short)f2bf(a.y);
  r[2] = (short)f2bf(a.z); r[3] = (short)f2bf(a.w);
  r[4] = (short)f2bf(b.x); r[5] = (short)f2bf(b.y);
  r[6] = (short)f2bf(b.z); r[7] = (short)f2bf(b.w);
  *(short8*)(o + (size_t)i * 8) = r;
}

// ---- async global->LDS, width 16 ------------------------------------------
__device__ __forceinline__ void gload16(const u16* g, u16* l) {
  __builtin_amdgcn_global_load_lds(
      (const __attribute__((address_space(1))) void*)g,
      (__attribute__((address_space(3))) void*)l, 16, 0, 0);
}

// Stage one half-tile (128 rows x 64 cols bf16 = 16 KB) into LDS.
// LDS dest linear; T2 swizzle applied by permuting the GLOBAL source chunk.
__device__ __forceinline__ void stage_half(const u16* __restrict__ gRowBase,
                                           int k0, u16* ldsHalf, int tid) {
#pragma unroll
  for (int i = 0; i < 2; ++i) {
    int p = i * 512 + tid;                 // dest 16B-chunk, 0..1023
    int row = p >> 3;
    int c = (p & 7) ^ (row & 7);           // involutive swizzle
    gload16(gRowBase + (size_t)row * KK + k0 + c * 8, ldsHalf + p * 8);
  }
}

// Swizzled ds_read of one 16B MFMA fragment: logical (row r, chunk q).
__device__ __forceinline__ short8 ldsfrag(const u16* base, int r, int q) {
  return *(const short8*)(base + r * 64 + (((q ^ r) & 7) << 3));
}

#define MFMA16(a, b, c) __builtin_amdgcn_mfma_f32_16x16x32_bf16(a, b, c, 0, 0, 0)

// ---- 256x256-tile, 4-phase/K-tile, read-one-phase-ahead pipeline -----------
// Reads issued in phase k are consumed in phase k+1 (or later) -> drain under
// MFMA. bfr banks alternate per tile (caller unrolls x2 with swapped refs).
template <int MODE>  // 0 = steady (t<=61), 1 = t==62, 2 = t==63
__device__ __forceinline__ void do_tile(
    int t, f32x4 (&acc)[8][4], const u16* Ag, const u16* Wg, u16* sh,
    int tid, int lr, int hi, int wr, int wc,
    short8 (&afrA)[4][2], short8 (&afrB)[4][2],
    short8 (&bfrC)[4][2], short8 (&bfrN)[4][2]) {
  const int b = t & 1;
  u16* Acur = ABUF(sh, b);
  u16* Anxt = ABUF(sh, b ^ 1);
  u16* Bcur = BBUF(sh, b);
  u16* Bnxt = BBUF(sh, b ^ 1);

  // ---- P1: stage A1(t+1) -> Anxt hi. MFMA Q00 (operands pre-read last tile).
  if (MODE <= 1) stage_half(Ag + 128 * KK, (t + 1) * 64, Anxt + 8192, tid);
  FENCE; BAR;
  __builtin_amdgcn_s_setprio(1);
#pragma unroll
  for (int m = 0; m < 4; ++m)
#pragma unroll
    for (int n = 0; n < 2; ++n)
#pragma unroll
      for (int ks = 0; ks < 2; ++ks)
        acc[m][n] = MFMA16(afrA[m][ks], bfrC[n][ks], acc[m][n]);
  __builtin_amdgcn_s_setprio(0);
  FENCE; BAR;

  // ---- P2: drain A1(t); read afrB = A-mh1(t); stage B0(t+2) -> Bcur lo.
  if (MODE <= 1) { WAITVM(8); } else { WAITVM(0); }
#pragma unroll
  for (int m = 0; m < 4; ++m)
#pragma unroll
    for (int ks = 0; ks < 2; ++ks)
      afrB[m][ks] = ldsfrag(Acur, wr * 128 + 64 + m * 16 + lr, ks * 4 + hi);
  if (MODE == 0) stage_half(Wg, (t + 2) * 64, Bcur, tid);
  FENCE; BAR;
  __builtin_amdgcn_s_setprio(1);
#pragma unroll
  for (int m = 0; m < 4; ++m)
#pragma unroll
    for (int n = 0; n < 2; ++n)
#pragma unroll
      for (int ks = 0; ks < 2; ++ks)
        acc[m][2 + n] = MFMA16(afrA[m][ks], bfrC[2 + n][ks], acc[m][2 + n]);
  __builtin_amdgcn_s_setprio(0);
  FENCE; BAR;

  // ---- P3: drain B0/B1/A0(t+1); read bfrN = B(t+1); stage B1(t+2) -> Bcur hi.
  if (MODE == 0) { WAITVM(4); } else if (MODE == 1) { WAITVM(2); }
  if (MODE <= 1) {
#pragma unroll
    for (int n = 0; n < 4; ++n)
#pragma unroll
      for (int ks = 0; ks < 2; ++ks)
        bfrN[n][ks] = ldsfrag(Bnxt, wc * 64 + n * 16 + lr, ks * 4 + hi);
  }
  if (MODE == 0) stage_half(Wg + 128 * KK, (t + 2) * 64, Bcur + 8192, tid);
  FENCE; BAR;
  __builtin_amdgcn_s_setprio(1);
#pragma unroll
  for (int m = 0; m < 4; ++m)
#pragma unroll
    for (int n = 0; n < 2; ++n)
#pragma unroll
      for (int ks = 0; ks < 2; ++ks)
        acc[4 + m][n] = MFMA16(afrB[m][ks], bfrC[n][ks], acc[4 + m][n]);
  __builtin_amdgcn_s_setprio(0);
  FENCE; BAR;

  // ---- P4: read afrA = A-mh0(t+1); stage A0(t+2) -> Acur lo.
  if (MODE <= 1) {
#pragma unroll
    for (int m = 0; m < 4; ++m)
#pragma unroll
      for (int ks = 0; ks < 2; ++ks)
        afrA[m][ks] = ldsfrag(Anxt, wr * 128 + m * 16 + lr, ks * 4 + hi);
  }
  if (MODE == 0) stage_half(Ag, (t + 2) * 64, Acur, tid);
  FENCE; BAR;
  __builtin_amdgcn_s_setprio(1);
#pragma unroll
  for (int m = 0; m < 4; ++m)
#pragma unroll
    for (int n = 0; n < 2; ++n)
#pragma unroll
      for (int ks = 0; ks < 2; ++ks)
        acc[4 + m][2 + n] = MFMA16(afrB[m][ks], bfrC[2 + n][ks], acc[4 + m][2 + n]);
  __builtin_amdgcn_s_setprio(0);
  FENCE; BAR;
}

__global__ __launch_bounds__(512, 2) void gemm_k(const u16* __restrict__ A,
                                                 const u16* __restrict__ W,
                                                 const float* __restrict__ scales,
                                                 const float* __restrict__ bias,
                                                 float* __restrict__ out) {
  __shared__ u16 sh[4 * 16384];  // 128 KiB

  // T1: XCD-aware swizzle (nwg = 256, divisible by 8)
  const int cpx = gridDim.x >> 3;
  const int wg = (blockIdx.x & 7) * cpx + (blockIdx.x >> 3);
  const int bm = wg >> 4;
  const int bn = wg & 15;

  const int tid = threadIdx.x;
  const int lane = tid & 63;
  const int lr = lane & 15;
  const int hi = lane >> 4;
  const int wid = tid >> 6;
  const int wr = wid >> 2;  // 2 (M) x 4 (N) wave grid; wave tile 128x64
  const int wc = wid & 3;

  f32x4 acc[8][4] = {};
  short8 afrA[4][2], afrB[4][2], bfrE[4][2], bfrO[4][2];

  const u16* Ag = A + (size_t)bm * 256 * KK;
  const u16* Wg = W + (size_t)bn * 256 * KK;

  // ---- prologue: tile0 fully staged; pre-read bfrE=B(0), afrA=A-mh0(0);
  //      then mimic P2/P3/P4(-1): stage B0(1),B1(1),A0(1).
  stage_half(Wg,             0, BBUF(sh, 0),        tid);
  stage_half(Wg + 128 * KK,  0, BBUF(sh, 0) + 8192, tid);
  stage_half(Ag,             0, ABUF(sh, 0),        tid);
  stage_half(Ag + 128 * KK,  0, ABUF(sh, 0) + 8192, tid);
  WAITVM(0);
  BAR;
#pragma unroll
  for (int n = 0; n < 4; ++n)
#pragma unroll
    for (int ks = 0; ks < 2; ++ks)
      bfrE[n][ks] = ldsfrag(BBUF(sh, 0), wc * 64 + n * 16 + lr, ks * 4 + hi);
#pragma unroll
  for (int m = 0; m < 4; ++m)
#pragma unroll
    for (int ks = 0; ks < 2; ++ks)
      afrA[m][ks] = ldsfrag(ABUF(sh, 0), wr * 128 + m * 16 + lr, ks * 4 + hi);
  stage_half(Wg,            64, BBUF(sh, 1),        tid);
  stage_half(Wg + 128 * KK, 64, BBUF(sh, 1) + 8192, tid);
  stage_half(Ag,            64, ABUF(sh, 1),        tid);

  // ---- main loop: unrolled x2 so bfr banks alternate with static names
  for (int tt = 0; tt < 31; ++tt) {
    do_tile<0>(tt * 2,     acc, Ag, Wg, sh, tid, lr, hi, wr, wc, afrA, afrB, bfrE, bfrO);
    do_tile<0>(tt * 2 + 1, acc, Ag, Wg, sh, tid, lr, hi, wr, wc, afrA, afrB, bfrO, bfrE);
  }
  do_tile<1>(62, acc, Ag, Wg, sh, tid, lr, hi, wr, wc, afrA, afrB, bfrE, bfrO);
  do_tile<2>(63, acc, Ag, Wg, sh, tid, lr, hi, wr, wc, afrA, afrB, bfrO, bfrE);

  // ---- epilogue: coalesced fp32 stores via LDS transpose (2 rounds) -------
  float* shf = (float*)sh;
  const int colg = (tid & 63) * 4;
  const int cslot = colg >> 6;
  const int cin = colg & 63;
  const int gcol = bn * 256 + colg;
  const f32x4 s4 = *(const f32x4*)(scales + gcol);
  const f32x4 b4 = *(const f32x4*)(bias + gcol);
  const int rlo = tid >> 6;

#pragma unroll
  for (int h = 0; h < 2; ++h) {
    if (h) BAR;
    if (wr == h) {
      const int wbase = wc * 8192;
#pragma unroll
      for (int m = 0; m < 8; ++m)
#pragma unroll
        for (int n = 0; n < 4; ++n) {
          const int colw = (n * 16 + lr) ^ (hi << 4);
#pragma unroll
          for (int j = 0; j < 4; ++j)
            shf[wbase + (m * 16 + hi * 4 + j) * 64 + colw] = acc[m][n][j];
        }
    }
    FENCE; BAR;
#pragma unroll
    for (int it = 0; it < 16; ++it) {
      const int roww = it * 8 + rlo;
      const int X = ((roww >> 2) & 3) << 4;
      f32x4 v = *(const f32x4*)(shf + cslot * 8192 + roww * 64 + (cin ^ X));
      v = v * s4 + b4;
      *(f32x4*)(out + (size_t)(bm * 256 + h * 128 + roww) * NN + gcol) = v;
    }
  }
}

// ---- fallback (ws too small): correct but slow -----------------------------
__global__ __launch_bounds__(256) void fb_k(const float* __restrict__ A,
                                            const int* __restrict__ W,
                                            const float* __restrict__ scales,
                                            const float* __restrict__ bias,
                                            float* __restrict__ out) {
  __shared__ float Arow[KK];
  const int m = blockIdx.y;
  const int n0 = blockIdx.x * 256;
  const int tid = threadIdx.x;
  for (int k = tid; k < KK; k += 256) Arow[k] = A[(size_t)m * KK + k];
  __syncthreads();
  const int n = n0 + tid;
  float acc = 0.f;
  const int* wrp = W + (size_t)n * KK;
  for (int k = 0; k < KK; ++k) acc += Arow[k] * (float)wrp[k];
  out[(size_t)m * NN + n] = acc * scales[n] + bias[n];
}

extern "C" void kernel_launch(void* const* d_in, const int* in_sizes, int n_in,
                              void* d_out, int out_size, void* d_ws, size_t ws_size,
                              hipStream_t stream) {
  const float* input = (const float*)d_in[0];
  const int* w8 = (const int*)d_in[1];
  const float* scales = (const float*)d_in[2];
  const float* bias = (const float*)d_in[3];
  float* out = (float*)d_out;

  const size_t nelem = (size_t)NN * KK;
  const size_t need = 2 * nelem * sizeof(u16);

  if (ws_size >= need) {
    u16* Wbf = (u16*)d_ws;
    u16* Abf = Wbf + nelem;
    cvt_w_k<<<8192, 256, 0, stream>>>(w8, Wbf);
    cvt_a_k<<<8192, 256, 0, stream>>>(input, Abf);
    gemm_k<<<256, 512, 0, stream>>>(Abf, Wbf, scales, bias, out);
  } else {
    dim3 grid(NN / 256, MM);
    fb_k<<<grid, 256, 0, stream>>>(input, w8, scales, bias, out);
  }
}

// Round 6
// 424.037 us; speedup vs baseline: 1.0003x; 1.0003x over previous
//
#include <hip/hip_runtime.h>
#include <hip/hip_bf16.h>

typedef unsigned short u16;
typedef unsigned int u32;
typedef __attribute__((ext_vector_type(8))) short short8;
typedef __attribute__((ext_vector_type(4))) float f32x4;

#define MM 4096
#define NN 4096
#define KK 4096

#define BAR __builtin_amdgcn_s_barrier()
#define FENCE asm volatile("" ::: "memory")
#define WAITVM(n) asm volatile("s_waitcnt vmcnt(" #n ")" ::: "memory")

// LDS layout: Ab0 @0, Bb0 @16384, Ab1 @32768, Bb1 @49152 (u16 elements)
#define ABUF(sh, b) ((sh) + (b) * 32768)
#define BBUF(sh, b) ((sh) + 16384 + (b) * 32768)

__device__ __forceinline__ u16 f2bf(float f) {
  union { float f; u32 u; } v; v.f = f;
  u32 r = v.u + 0x7fffu + ((v.u >> 16) & 1u);
  return (u16)(r >> 16);
}

// ---- conversion passes (linear) --------------------------------------------
__global__ __launch_bounds__(256) void cvt_w_k(const int* __restrict__ w,
                                               u16* __restrict__ o) {
  int i = blockIdx.x * 256 + threadIdx.x;
  const int4* w4 = (const int4*)w;
  int4 a = w4[2 * i];
  int4 b = w4[2 * i + 1];
  short8 r;
  r[0] = (short)f2bf((float)a.x); r[1] = (short)f2bf((float)a.y);
  r[2] = (short)f2bf((float)a.z); r[3] = (short)f2bf((float)a.w);
  r[4] = (short)f2bf((float)b.x); r[5] = (short)f2bf((float)b.y);
  r[6] = (short)f2bf((float)b.z); r[7] = (short)f2bf((float)b.w);
  *(short8*)(o + (size_t)i * 8) = r;
}

__global__ __launch_bounds__(256) void cvt_a_k(const float* __restrict__ x,
                                               u16* __restrict__ o) {
  int i = blockIdx.x * 256 + threadIdx.x;
  const float4* x4 = (const float4*)x;
  float4 a = x4[2 * i];
  float4 b = x4[2 * i + 1];
  short8 r;
  r[0] = (short)f2bf(a.x); r[1] = (short)f2bf(a.y);
  r[2] = (short)f2bf(a.z); r[3] = (short)f2bf(a.w);
  r[4] = (short)f2bf(b.x); r[5] = (short)f2bf(b.y);
  r[6] = (short)f2bf(b.z); r[7] = (short)f2bf(b.w);
  *(short8*)(o + (size_t)i * 8) = r;
}

// ---- async global->LDS, width 16 ------------------------------------------
__device__ __forceinline__ void gload16(const u16* g, u16* l) {
  __builtin_amdgcn_global_load_lds(
      (const __attribute__((address_space(1))) void*)g,
      (__attribute__((address_space(3))) void*)l, 16, 0, 0);
}

// Stage one half-tile (128 rows x 64 cols bf16 = 16 KB) into LDS.
// LDS dest linear; T2 swizzle applied by permuting the GLOBAL source chunk.
__device__ __forceinline__ void stage_half(const u16* __restrict__ gRowBase,
                                           int k0, u16* ldsHalf, int tid) {
#pragma unroll
  for (int i = 0; i < 2; ++i) {
    int p = i * 512 + tid;                 // dest 16B-chunk, 0..1023
    int row = p >> 3;
    int c = (p & 7) ^ (row & 7);           // involutive swizzle
    gload16(gRowBase + (size_t)row * KK + k0 + c * 8, ldsHalf + p * 8);
  }
}

// Swizzled ds_read of one 16B MFMA fragment: logical (row r, chunk q).
__device__ __forceinline__ short8 ldsfrag(const u16* base, int r, int q) {
  return *(const short8*)(base + r * 64 + (((q ^ r) & 7) << 3));
}

#define MFMA16(a, b, c) __builtin_amdgcn_mfma_f32_16x16x32_bf16(a, b, c, 0, 0, 0)

// ---- 256x256-tile, 4-phase/K-tile, read-one-phase-ahead pipeline -----------
template <int MODE>  // 0 = steady (t<=61), 1 = t==62, 2 = t==63
__device__ __forceinline__ void do_tile(
    int t, f32x4 (&acc)[8][4], const u16* Ag, const u16* Wg, u16* sh,
    int tid, int lr, int hi, int wr, int wc,
    short8 (&afrA)[4][2], short8 (&afrB)[4][2],
    short8 (&bfrC)[4][2], short8 (&bfrN)[4][2]) {
  const int b = t & 1;
  u16* Acur = ABUF(sh, b);
  u16* Anxt = ABUF(sh, b ^ 1);
  u16* Bcur = BBUF(sh, b);
  u16* Bnxt = BBUF(sh, b ^ 1);

  // ---- P1: stage A1(t+1) -> Anxt hi. MFMA Q00 (operands pre-read last tile).
  if (MODE <= 1) stage_half(Ag + 128 * KK, (t + 1) * 64, Anxt + 8192, tid);
  FENCE; BAR;
  __builtin_amdgcn_s_setprio(1);
#pragma unroll
  for (int m = 0; m < 4; ++m)
#pragma unroll
    for (int n = 0; n < 2; ++n)
#pragma unroll
      for (int ks = 0; ks < 2; ++ks)
        acc[m][n] = MFMA16(afrA[m][ks], bfrC[n][ks], acc[m][n]);
  __builtin_amdgcn_s_setprio(0);
  FENCE; BAR;

  // ---- P2: drain A1(t); read afrB = A-mh1(t); stage B0(t+2) -> Bcur lo.
  if (MODE <= 1) { WAITVM(8); } else { WAITVM(0); }
#pragma unroll
  for (int m = 0; m < 4; ++m)
#pragma unroll
    for (int ks = 0; ks < 2; ++ks)
      afrB[m][ks] = ldsfrag(Acur, wr * 128 + 64 + m * 16 + lr, ks * 4 + hi);
  if (MODE == 0) stage_half(Wg, (t + 2) * 64, Bcur, tid);
  FENCE; BAR;
  __builtin_amdgcn_s_setprio(1);
#pragma unroll
  for (int m = 0; m < 4; ++m)
#pragma unroll
    for (int n = 0; n < 2; ++n)
#pragma unroll
      for (int ks = 0; ks < 2; ++ks)
        acc[m][2 + n] = MFMA16(afrA[m][ks], bfrC[2 + n][ks], acc[m][2 + n]);
  __builtin_amdgcn_s_setprio(0);
  FENCE; BAR;

  // ---- P3: drain B0/B1/A0(t+1); read bfrN = B(t+1); stage B1(t+2) -> Bcur hi.
  if (MODE == 0) { WAITVM(4); } else if (MODE == 1) { WAITVM(2); }
  if (MODE <= 1) {
#pragma unroll
    for (int n = 0; n < 4; ++n)
#pragma unroll
      for (int ks = 0; ks < 2; ++ks)
        bfrN[n][ks] = ldsfrag(Bnxt, wc * 64 + n * 16 + lr, ks * 4 + hi);
  }
  if (MODE == 0) stage_half(Wg + 128 * KK, (t + 2) * 64, Bcur + 8192, tid);
  FENCE; BAR;
  __builtin_amdgcn_s_setprio(1);
#pragma unroll
  for (int m = 0; m < 4; ++m)
#pragma unroll
    for (int n = 0; n < 2; ++n)
#pragma unroll
      for (int ks = 0; ks < 2; ++ks)
        acc[4 + m][n] = MFMA16(afrB[m][ks], bfrC[n][ks], acc[4 + m][n]);
  __builtin_amdgcn_s_setprio(0);
  FENCE; BAR;

  // ---- P4: read afrA = A-mh0(t+1); stage A0(t+2) -> Acur lo.
  if (MODE <= 1) {
#pragma unroll
    for (int m = 0; m < 4; ++m)
#pragma unroll
      for (int ks = 0; ks < 2; ++ks)
        afrA[m][ks] = ldsfrag(Anxt, wr * 128 + m * 16 + lr, ks * 4 + hi);
  }
  if (MODE == 0) stage_half(Ag, (t + 2) * 64, Acur, tid);
  FENCE; BAR;
  __builtin_amdgcn_s_setprio(1);
#pragma unroll
  for (int m = 0; m < 4; ++m)
#pragma unroll
    for (int n = 0; n < 2; ++n)
#pragma unroll
      for (int ks = 0; ks < 2; ++ks)
        acc[4 + m][2 + n] = MFMA16(afrB[m][ks], bfrC[2 + n][ks], acc[4 + m][2 + n]);
  __builtin_amdgcn_s_setprio(0);
  FENCE; BAR;
}

// NOTE: min-waves-per-EU = 1 (not 2). LDS (128 KiB) already caps residency at
// 1 block/CU (2 waves/SIMD); asking for 2 only halves the register budget to
// 256 and caused the r5 scratch-spill catastrophe (+670 MB HBM traffic).
__global__ __launch_bounds__(512, 1) void gemm_k(const u16* __restrict__ A,
                                                 const u16* __restrict__ W,
                                                 const float* __restrict__ scales,
                                                 const float* __restrict__ bias,
                                                 float* __restrict__ out) {
  __shared__ u16 sh[4 * 16384];  // 128 KiB

  // T1: XCD-aware swizzle (nwg = 256, divisible by 8)
  const int cpx = gridDim.x >> 3;
  const int wg = (blockIdx.x & 7) * cpx + (blockIdx.x >> 3);
  const int bm = wg >> 4;
  const int bn = wg & 15;

  const int tid = threadIdx.x;
  const int lane = tid & 63;
  const int lr = lane & 15;
  const int hi = lane >> 4;
  const int wid = tid >> 6;
  const int wr = wid >> 2;  // 2 (M) x 4 (N) wave grid; wave tile 128x64
  const int wc = wid & 3;

  f32x4 acc[8][4] = {};
  short8 afrA[4][2], afrB[4][2], bfrE[4][2], bfrO[4][2];

  const u16* Ag = A + (size_t)bm * 256 * KK;
  const u16* Wg = W + (size_t)bn * 256 * KK;

  // ---- prologue: tile0 fully staged; pre-read bfrE=B(0), afrA=A-mh0(0);
  //      then stage B0(1),B1(1),A0(1).
  stage_half(Wg,             0, BBUF(sh, 0),        tid);
  stage_half(Wg + 128 * KK,  0, BBUF(sh, 0) + 8192, tid);
  stage_half(Ag,             0, ABUF(sh, 0),        tid);
  stage_half(Ag + 128 * KK,  0, ABUF(sh, 0) + 8192, tid);
  WAITVM(0);
  BAR;
#pragma unroll
  for (int n = 0; n < 4; ++n)
#pragma unroll
    for (int ks = 0; ks < 2; ++ks)
      bfrE[n][ks] = ldsfrag(BBUF(sh, 0), wc * 64 + n * 16 + lr, ks * 4 + hi);
#pragma unroll
  for (int m = 0; m < 4; ++m)
#pragma unroll
    for (int ks = 0; ks < 2; ++ks)
      afrA[m][ks] = ldsfrag(ABUF(sh, 0), wr * 128 + m * 16 + lr, ks * 4 + hi);
  stage_half(Wg,            64, BBUF(sh, 1),        tid);
  stage_half(Wg + 128 * KK, 64, BBUF(sh, 1) + 8192, tid);
  stage_half(Ag,            64, ABUF(sh, 1),        tid);

  // ---- main loop: unrolled x2 so bfr banks alternate with static names
  for (int tt = 0; tt < 31; ++tt) {
    do_tile<0>(tt * 2,     acc, Ag, Wg, sh, tid, lr, hi, wr, wc, afrA, afrB, bfrE, bfrO);
    do_tile<0>(tt * 2 + 1, acc, Ag, Wg, sh, tid, lr, hi, wr, wc, afrA, afrB, bfrO, bfrE);
  }
  do_tile<1>(62, acc, Ag, Wg, sh, tid, lr, hi, wr, wc, afrA, afrB, bfrE, bfrO);
  do_tile<2>(63, acc, Ag, Wg, sh, tid, lr, hi, wr, wc, afrA, afrB, bfrO, bfrE);

  // ---- epilogue: coalesced fp32 stores via LDS transpose (2 rounds) -------
  float* shf = (float*)sh;
  const int colg = (tid & 63) * 4;
  const int cslot = colg >> 6;
  const int cin = colg & 63;
  const int gcol = bn * 256 + colg;
  const f32x4 s4 = *(const f32x4*)(scales + gcol);
  const f32x4 b4 = *(const f32x4*)(bias + gcol);
  const int rlo = tid >> 6;

#pragma unroll
  for (int h = 0; h < 2; ++h) {
    if (h) BAR;
    if (wr == h) {
      const int wbase = wc * 8192;
#pragma unroll
      for (int m = 0; m < 8; ++m)
#pragma unroll
        for (int n = 0; n < 4; ++n) {
          const int colw = (n * 16 + lr) ^ (hi << 4);
#pragma unroll
          for (int j = 0; j < 4; ++j)
            shf[wbase + (m * 16 + hi * 4 + j) * 64 + colw] = acc[m][n][j];
        }
    }
    FENCE; BAR;
#pragma unroll
    for (int it = 0; it < 16; ++it) {
      const int roww = it * 8 + rlo;
      const int X = ((roww >> 2) & 3) << 4;
      f32x4 v = *(const f32x4*)(shf + cslot * 8192 + roww * 64 + (cin ^ X));
      v = v * s4 + b4;
      *(f32x4*)(out + (size_t)(bm * 256 + h * 128 + roww) * NN + gcol) = v;
    }
  }
}

// ---- fallback (ws too small): correct but slow -----------------------------
__global__ __launch_bounds__(256) void fb_k(const float* __restrict__ A,
                                            const int* __restrict__ W,
                                            const float* __restrict__ scales,
                                            const float* __restrict__ bias,
                                            float* __restrict__ out) {
  __shared__ float Arow[KK];
  const int m = blockIdx.y;
  const int n0 = blockIdx.x * 256;
  const int tid = threadIdx.x;
  for (int k = tid; k < KK; k += 256) Arow[k] = A[(size_t)m * KK + k];
  __syncthreads();
  const int n = n0 + tid;
  float acc = 0.f;
  const int* wrp = W + (size_t)n * KK;
  for (int k = 0; k < KK; ++k) acc += Arow[k] * (float)wrp[k];
  out[(size_t)m * NN + n] = acc * scales[n] + bias[n];
}

extern "C" void kernel_launch(void* const* d_in, const int* in_sizes, int n_in,
                              void* d_out, int out_size, void* d_ws, size_t ws_size,
                              hipStream_t stream) {
  const float* input = (const float*)d_in[0];
  const int* w8 = (const int*)d_in[1];
  const float* scales = (const float*)d_in[2];
  const float* bias = (const float*)d_in[3];
  float* out = (float*)d_out;

  const size_t nelem = (size_t)NN * KK;
  const size_t need = 2 * nelem * sizeof(u16);

  if (ws_size >= need) {
    u16* Wbf = (u16*)d_ws;
    u16* Abf = Wbf + nelem;
    cvt_w_k<<<8192, 256, 0, stream>>>(w8, Wbf);
    cvt_a_k<<<8192, 256, 0, stream>>>(input, Abf);
    gemm_k<<<256, 512, 0, stream>>>(Abf, Wbf, scales, bias, out);
  } else {
    dim3 grid(NN / 256, MM);
    fb_k<<<grid, 256, 0, stream>>>(input, w8, scales, bias, out);
  }
}

// Round 7
// 147.726 us; speedup vs baseline: 2.8712x; 2.8704x over previous
//
#include <hip/hip_runtime.h>
#include <hip/hip_bf16.h>

typedef unsigned short u16;
typedef unsigned int u32;
typedef __attribute__((ext_vector_type(8))) short short8;
typedef __attribute__((ext_vector_type(4))) float f32x4;

#define MM 4096
#define NN 4096
#define KK 4096

#define BAR __builtin_amdgcn_s_barrier()
#define FENCE asm volatile("" ::: "memory")
#define WAITVM(n) asm volatile("s_waitcnt vmcnt(" #n ")" ::: "memory")

// LDS layout: Ab0 @0, Bb0 @16384, Ab1 @32768, Bb1 @49152 (u16 elements)
#define ABUF(sh, b) ((sh) + (b) * 32768)
#define BBUF(sh, b) ((sh) + 16384 + (b) * 32768)

__device__ __forceinline__ u16 f2bf(float f) {
  union { float f; u32 u; } v; v.f = f;
  u32 r = v.u + 0x7fffu + ((v.u >> 16) & 1u);
  return (u16)(r >> 16);
}

// ---- conversion passes (linear) --------------------------------------------
__global__ __launch_bounds__(256) void cvt_w_k(const int* __restrict__ w,
                                               u16* __restrict__ o) {
  int i = blockIdx.x * 256 + threadIdx.x;
  const int4* w4 = (const int4*)w;
  int4 a = w4[2 * i];
  int4 b = w4[2 * i + 1];
  short8 r;
  r[0] = (short)f2bf((float)a.x); r[1] = (short)f2bf((float)a.y);
  r[2] = (short)f2bf((float)a.z); r[3] = (short)f2bf((float)a.w);
  r[4] = (short)f2bf((float)b.x); r[5] = (short)f2bf((float)b.y);
  r[6] = (short)f2bf((float)b.z); r[7] = (short)f2bf((float)b.w);
  *(short8*)(o + (size_t)i * 8) = r;
}

__global__ __launch_bounds__(256) void cvt_a_k(const float* __restrict__ x,
                                               u16* __restrict__ o) {
  int i = blockIdx.x * 256 + threadIdx.x;
  const float4* x4 = (const float4*)x;
  float4 a = x4[2 * i];
  float4 b = x4[2 * i + 1];
  short8 r;
  r[0] = (short)f2bf(a.x); r[1] = (short)f2bf(a.y);
  r[2] = (short)f2bf(a.z); r[3] = (short)f2bf(a.w);
  r[4] = (short)f2bf(b.x); r[5] = (short)f2bf(b.y);
  r[6] = (short)f2bf(b.z); r[7] = (short)f2bf(b.w);
  *(short8*)(o + (size_t)i * 8) = r;
}

// ---- async global->LDS, width 16 ------------------------------------------
__device__ __forceinline__ void gload16(const u16* g, u16* l) {
  __builtin_amdgcn_global_load_lds(
      (const __attribute__((address_space(1))) void*)g,
      (__attribute__((address_space(3))) void*)l, 16, 0, 0);
}

// Stage one half-tile (128 rows x 64 cols bf16 = 16 KB) into LDS.
// LDS dest linear; T2 swizzle applied by permuting the GLOBAL source chunk.
__device__ __forceinline__ void stage_half(const u16* __restrict__ gRowBase,
                                           int k0, u16* ldsHalf, int tid) {
#pragma unroll
  for (int i = 0; i < 2; ++i) {
    int p = i * 512 + tid;                 // dest 16B-chunk, 0..1023
    int row = p >> 3;
    int c = (p & 7) ^ (row & 7);           // involutive swizzle
    gload16(gRowBase + (size_t)row * KK + k0 + c * 8, ldsHalf + p * 8);
  }
}

// Swizzled ds_read of one 16B MFMA fragment: logical (row r, chunk q).
__device__ __forceinline__ short8 ldsfrag(const u16* base, int r, int q) {
  return *(const short8*)(base + r * 64 + (((q ^ r) & 7) << 3));
}

#define MFMA16(a, b, c) __builtin_amdgcn_mfma_f32_16x16x32_bf16(a, b, c, 0, 0, 0)

// ---- 256x256-tile, 4-phase/K-tile, m201-style 12/4/8/0 read spread ---------
// All reads consumed within their tile (register budget 192 < 256 hard cap).
// Stage choreography (race-free under spread reads):
//   P1: A1(t+1)->Anxt-hi   (Anxt last read at P3(t-1))
//   P3: B0(t+2)->Bcur-lo   (B last read at P2(t))
//   P4: B1(t+2)->Bcur-hi, A0(t+2)->Acur-lo; vmcnt(6) (drains tile t+1 exactly)
template <int MODE>  // 0 = steady (t<=61), 1 = t==62, 2 = t==63
__device__ __forceinline__ void do_tile(
    int t, f32x4 (&acc)[8][4], const u16* Ag, const u16* Wg, u16* sh,
    int tid, int lr, int hi, int wr, int wc) {
  const int b = t & 1;
  u16* Acur = ABUF(sh, b);
  u16* Anxt = ABUF(sh, b ^ 1);
  u16* Bcur = BBUF(sh, b);
  short8 bfr[4][2], afr[4][2];

  // ---- P1: read bfr01 (4) + afr mh0 (8); stage A1(t+1).
#pragma unroll
  for (int n = 0; n < 2; ++n)
#pragma unroll
    for (int ks = 0; ks < 2; ++ks)
      bfr[n][ks] = ldsfrag(Bcur, wc * 64 + n * 16 + lr, ks * 4 + hi);
#pragma unroll
  for (int m = 0; m < 4; ++m)
#pragma unroll
    for (int ks = 0; ks < 2; ++ks)
      afr[m][ks] = ldsfrag(Acur, wr * 128 + m * 16 + lr, ks * 4 + hi);
  if (MODE <= 1) stage_half(Ag + 128 * KK, (t + 1) * 64, Anxt + 8192, tid);
  asm volatile("s_waitcnt lgkmcnt(8)" ::: "memory");  // bound arrival skew
  FENCE; BAR;
  __builtin_amdgcn_s_setprio(1);
#pragma unroll
  for (int m = 0; m < 4; ++m)
#pragma unroll
    for (int n = 0; n < 2; ++n)
#pragma unroll
      for (int ks = 0; ks < 2; ++ks)
        acc[m][n] = MFMA16(afr[m][ks], bfr[n][ks], acc[m][n]);
  __builtin_amdgcn_s_setprio(0);
  FENCE; BAR;

  // ---- P2: read bfr23 (4); no stage.
#pragma unroll
  for (int n = 2; n < 4; ++n)
#pragma unroll
    for (int ks = 0; ks < 2; ++ks)
      bfr[n][ks] = ldsfrag(Bcur, wc * 64 + n * 16 + lr, ks * 4 + hi);
  FENCE; BAR;
  __builtin_amdgcn_s_setprio(1);
#pragma unroll
  for (int m = 0; m < 4; ++m)
#pragma unroll
    for (int n = 0; n < 2; ++n)
#pragma unroll
      for (int ks = 0; ks < 2; ++ks)
        acc[m][2 + n] = MFMA16(afr[m][ks], bfr[2 + n][ks], acc[m][2 + n]);
  __builtin_amdgcn_s_setprio(0);
  FENCE; BAR;

  // ---- P3: read afr mh1 (8, overwrites); stage B0(t+2)->Bcur lo.
#pragma unroll
  for (int m = 0; m < 4; ++m)
#pragma unroll
    for (int ks = 0; ks < 2; ++ks)
      afr[m][ks] = ldsfrag(Acur, wr * 128 + 64 + m * 16 + lr, ks * 4 + hi);
  if (MODE == 0) stage_half(Wg, (t + 2) * 64, Bcur, tid);
  FENCE; BAR;
  __builtin_amdgcn_s_setprio(1);
#pragma unroll
  for (int m = 0; m < 4; ++m)
#pragma unroll
    for (int n = 0; n < 2; ++n)
#pragma unroll
      for (int ks = 0; ks < 2; ++ks)
        acc[4 + m][n] = MFMA16(afr[m][ks], bfr[n][ks], acc[4 + m][n]);
  __builtin_amdgcn_s_setprio(0);
  FENCE; BAR;

  // ---- P4: stage B1(t+2)->Bcur hi + A0(t+2)->Acur lo; vmcnt once/tile.
  if (MODE == 0) {
    stage_half(Wg + 128 * KK, (t + 2) * 64, Bcur + 8192, tid);
    stage_half(Ag, (t + 2) * 64, Acur, tid);
    WAITVM(6);                 // drains exactly tile t+1's four halves
  } else if (MODE == 1) {
    WAITVM(0);                 // tail: tile 63 fully landed
  }
  FENCE; BAR;
  __builtin_amdgcn_s_setprio(1);
#pragma unroll
  for (int m = 0; m < 4; ++m)
#pragma unroll
    for (int n = 0; n < 2; ++n)
#pragma unroll
      for (int ks = 0; ks < 2; ++ks)
        acc[4 + m][2 + n] = MFMA16(afr[m][ks], bfr[2 + n][ks], acc[4 + m][2 + n]);
  __builtin_amdgcn_s_setprio(0);
  FENCE; BAR;
}

// (512,2): with 512-thread blocks, 2 waves/SIMD co-reside regardless ->
// per-wave budget is structurally 256 regs (r6 proved launch_bounds can't
// lift it). Loop state is sized to 192 regs to fit.
__global__ __launch_bounds__(512, 2) void gemm_k(const u16* __restrict__ A,
                                                 const u16* __restrict__ W,
                                                 const float* __restrict__ scales,
                                                 const float* __restrict__ bias,
                                                 float* __restrict__ out) {
  __shared__ u16 sh[4 * 16384];  // 128 KiB

  // T1: XCD-aware swizzle (nwg = 256, divisible by 8)
  const int cpx = gridDim.x >> 3;
  const int wg = (blockIdx.x & 7) * cpx + (blockIdx.x >> 3);
  const int bm = wg >> 4;
  const int bn = wg & 15;

  const int tid = threadIdx.x;
  const int lane = tid & 63;
  const int lr = lane & 15;
  const int hi = lane >> 4;
  const int wid = tid >> 6;
  const int wr = wid >> 2;  // 2 (M) x 4 (N) wave grid; wave tile 128x64
  const int wc = wid & 3;

  f32x4 acc[8][4] = {};

  const u16* Ag = A + (size_t)bm * 256 * KK;
  const u16* Wg = W + (size_t)bn * 256 * KK;

  // ---- prologue: tile0 all 4 halves + tile1 {B0,B1,A0}
  stage_half(Wg,             0, BBUF(sh, 0),        tid);
  stage_half(Wg + 128 * KK,  0, BBUF(sh, 0) + 8192, tid);
  stage_half(Ag,             0, ABUF(sh, 0),        tid);
  stage_half(Ag + 128 * KK,  0, ABUF(sh, 0) + 8192, tid);
  stage_half(Wg,            64, BBUF(sh, 1),        tid);
  stage_half(Wg + 128 * KK, 64, BBUF(sh, 1) + 8192, tid);
  stage_half(Ag,            64, ABUF(sh, 1),        tid);
  WAITVM(6);  // tile0 fully landed; tile1 {B0,B1,A0} in flight
  BAR;

  for (int t = 0; t < 62; ++t)
    do_tile<0>(t, acc, Ag, Wg, sh, tid, lr, hi, wr, wc);
  do_tile<1>(62, acc, Ag, Wg, sh, tid, lr, hi, wr, wc);
  do_tile<2>(63, acc, Ag, Wg, sh, tid, lr, hi, wr, wc);

  // ---- epilogue: dequant + bias, fp32 store (r3 direct-store version)
  // C/D layout (16x16x32): col = lane&15, row = (lane>>4)*4 + reg
  const int colb = bn * 256 + wc * 64 + lr;
  const int rowb0 = bm * 256 + wr * 128 + (hi << 2);
#pragma unroll
  for (int n = 0; n < 4; ++n) {
    const int col = colb + n * 16;
    const float sc = scales[col];
    const float bi = bias[col];
#pragma unroll
    for (int m = 0; m < 8; ++m) {
      const int row = rowb0 + m * 16;
#pragma unroll
      for (int j = 0; j < 4; ++j)
        out[(size_t)(row + j) * NN + col] = acc[m][n][j] * sc + bi;
    }
  }
}

// ---- fallback (ws too small): correct but slow -----------------------------
__global__ __launch_bounds__(256) void fb_k(const float* __restrict__ A,
                                            const int* __restrict__ W,
                                            const float* __restrict__ scales,
                                            const float* __restrict__ bias,
                                            float* __restrict__ out) {
  __shared__ float Arow[KK];
  const int m = blockIdx.y;
  const int n0 = blockIdx.x * 256;
  const int tid = threadIdx.x;
  for (int k = tid; k < KK; k += 256) Arow[k] = A[(size_t)m * KK + k];
  __syncthreads();
  const int n = n0 + tid;
  float acc = 0.f;
  const int* wrp = W + (size_t)n * KK;
  for (int k = 0; k < KK; ++k) acc += Arow[k] * (float)wrp[k];
  out[(size_t)m * NN + n] = acc * scales[n] + bias[n];
}

extern "C" void kernel_launch(void* const* d_in, const int* in_sizes, int n_in,
                              void* d_out, int out_size, void* d_ws, size_t ws_size,
                              hipStream_t stream) {
  const float* input = (const float*)d_in[0];
  const int* w8 = (const int*)d_in[1];
  const float* scales = (const float*)d_in[2];
  const float* bias = (const float*)d_in[3];
  float* out = (float*)d_out;

  const size_t nelem = (size_t)NN * KK;
  const size_t need = 2 * nelem * sizeof(u16);

  if (ws_size >= need) {
    u16* Wbf = (u16*)d_ws;
    u16* Abf = Wbf + nelem;
    cvt_w_k<<<8192, 256, 0, stream>>>(w8, Wbf);
    cvt_a_k<<<8192, 256, 0, stream>>>(input, Abf);
    gemm_k<<<256, 512, 0, stream>>>(Abf, Wbf, scales, bias, out);
  } else {
    dim3 grid(NN / 256, MM);
    fb_k<<<grid, 256, 0, stream>>>(input, w8, scales, bias, out);
  }
}

// Round 8
// 98.690 us; speedup vs baseline: 4.2978x; 1.4969x over previous
//
#include <hip/hip_runtime.h>
#include <hip/hip_bf16.h>

typedef unsigned short u16;
typedef unsigned int u32;
typedef unsigned char u8;
typedef __attribute__((ext_vector_type(4))) int i32x4;

#define MM 4096
#define NN 4096
#define KK 4096   // K in elements == bytes for int8

#define BAR __builtin_amdgcn_s_barrier()
#define FENCE asm volatile("" ::: "memory")
#define WAITVM(n) asm volatile("s_waitcnt vmcnt(" #n ")" ::: "memory")

// LDS (bytes): A0 @0, B0 @16384, A1 @32768, B1 @49152; halves +8192
#define ABUF(sh, b) ((sh) + (b) * 32768)
#define BBUF(sh, b) ((sh) + 16384 + (b) * 32768)

// ---- W: int32 -> packed int8 ----------------------------------------------
__global__ __launch_bounds__(256) void cvt_w_k(const int* __restrict__ w,
                                               u8* __restrict__ o) {
  int i = blockIdx.x * 256 + threadIdx.x;     // 16 int8 per thread
  const int4* w4 = (const int4*)w + (size_t)i * 4;
  i32x4 r;
#pragma unroll
  for (int j = 0; j < 4; ++j) {
    int4 v = w4[j];
    r[j] = (v.x & 255) | ((v.y & 255) << 8) | ((v.z & 255) << 16) | ((u32)(v.w & 255) << 24);
  }
  *(i32x4*)(o + (size_t)i * 16) = r;
}

// ---- A: fp32 -> int8 with per-row symmetric scale (one block per row) ------
__global__ __launch_bounds__(256) void cvt_a_k(const float* __restrict__ x,
                                               u8* __restrict__ o,
                                               float* __restrict__ dA) {
  const int row = blockIdx.x;
  const float4* xr = (const float4*)(x + (size_t)row * KK);
  const int t = threadIdx.x;
  float4 v[4];
  float mx = 0.f;
#pragma unroll
  for (int j = 0; j < 4; ++j) {
    v[j] = xr[t + j * 256];
    mx = fmaxf(mx, fmaxf(fmaxf(fabsf(v[j].x), fabsf(v[j].y)),
                         fmaxf(fabsf(v[j].z), fabsf(v[j].w))));
  }
#pragma unroll
  for (int off = 32; off; off >>= 1) mx = fmaxf(mx, __shfl_down(mx, off));
  __shared__ float sm[4];
  if ((t & 63) == 0) sm[t >> 6] = mx;
  __syncthreads();
  mx = fmaxf(fmaxf(sm[0], sm[1]), fmaxf(sm[2], sm[3]));
  mx = fmaxf(mx, 1e-20f);
  const float inv = 127.0f / mx;
  if (t == 0) dA[row] = mx / 127.0f;
  u32* orow = (u32*)(o + (size_t)row * KK);
#pragma unroll
  for (int j = 0; j < 4; ++j) {
    int qx = (int)rintf(v[j].x * inv), qy = (int)rintf(v[j].y * inv);
    int qz = (int)rintf(v[j].z * inv), qw = (int)rintf(v[j].w * inv);
    orow[t + j * 256] =
        (qx & 255) | ((qy & 255) << 8) | ((qz & 255) << 16) | ((u32)(qw & 255) << 24);
  }
}

// ---- async global->LDS, width 16 ------------------------------------------
__device__ __forceinline__ void gload16(const u8* g, u8* l) {
  __builtin_amdgcn_global_load_lds(
      (const __attribute__((address_space(1))) void*)g,
      (__attribute__((address_space(3))) void*)l, 16, 0, 0);
}

// Stage one half-tile (128 rows x 64 B) = 8 KB; ONE gload16 per thread.
// LDS dest linear; swizzle via permuted global source chunk: c = (p&3)^((row>>1)&3)
__device__ __forceinline__ void stage_half(const u8* __restrict__ gRowBase,
                                           int k0, u8* ldsHalf, int tid) {
  int row = tid >> 2;                        // 4 x16B chunks per 64B row
  int c = (tid & 3) ^ ((row >> 1) & 3);
  gload16(gRowBase + (size_t)row * KK + k0 + c * 16, ldsHalf + tid * 16);
}

// Swizzled read of one 16B i8 fragment at logical (row r, 16B-chunk q).
// 2-way bank aliasing only: (row&1) supplies the 64B bit, (row>>1)&3 spreads slots.
__device__ __forceinline__ i32x4 ldsfrag(const u8* base, int r, int q) {
  return *(const i32x4*)(base + r * 64 + (((q ^ (r >> 1)) & 3) << 4));
}

#define MFMAI8(a, b, c) __builtin_amdgcn_mfma_i32_16x16x64_i8(a, b, c, 0, 0, 0)

// ---- 256x256 tile, BK=64, 4-phase/K-tile, int8 ------------------------------
// Stage choreography: P1: A1(t+1); P3: B0(t+2); P4: B1(t+2)+A0(t+2), vmcnt(3)
// (1 gload/thread per half => queue counts: enter tile with 3 (t+1:B0,B1,A0);
//  P1 +1 -> 4; P3 +1 -> 5; P4 +2 -> 7; WAITVM(3) drains tile t+1's 4 halves.)
template <int MODE>  // 0 = steady (t<=61), 1 = t==62, 2 = t==63
__device__ __forceinline__ void do_tile(
    int t, i32x4 (&acc)[8][4], const u8* Ag, const u8* Wg, u8* sh,
    int tid, int lr, int hi, int wr, int wc) {
  const int b = t & 1;
  u8* Acur = ABUF(sh, b);
  u8* Anxt = ABUF(sh, b ^ 1);
  u8* Bcur = BBUF(sh, b);
  i32x4 bfr[4], afr[4];

  // ---- P1: read bfr01 + afr mh0 (6 reads); stage A1(t+1)
#pragma unroll
  for (int n = 0; n < 2; ++n)
    bfr[n] = ldsfrag(Bcur, wc * 64 + n * 16 + lr, hi);
#pragma unroll
  for (int m = 0; m < 4; ++m)
    afr[m] = ldsfrag(Acur, wr * 128 + m * 16 + lr, hi);
  if (MODE <= 1) stage_half(Ag + 128 * KK, (t + 1) * 64, Anxt + 8192, tid);
  FENCE; BAR;
  __builtin_amdgcn_s_setprio(1);
#pragma unroll
  for (int m = 0; m < 4; ++m)
#pragma unroll
    for (int n = 0; n < 2; ++n)
      acc[m][n] = MFMAI8(afr[m], bfr[n], acc[m][n]);
  __builtin_amdgcn_s_setprio(0);
  FENCE; BAR;

  // ---- P2: read bfr23 (2); no stage
#pragma unroll
  for (int n = 2; n < 4; ++n)
    bfr[n] = ldsfrag(Bcur, wc * 64 + n * 16 + lr, hi);
  FENCE; BAR;
  __builtin_amdgcn_s_setprio(1);
#pragma unroll
  for (int m = 0; m < 4; ++m)
#pragma unroll
    for (int n = 0; n < 2; ++n)
      acc[m][2 + n] = MFMAI8(afr[m], bfr[2 + n], acc[m][2 + n]);
  __builtin_amdgcn_s_setprio(0);
  FENCE; BAR;

  // ---- P3: read afr mh1 (4, overwrites); stage B0(t+2)
#pragma unroll
  for (int m = 0; m < 4; ++m)
    afr[m] = ldsfrag(Acur, wr * 128 + 64 + m * 16 + lr, hi);
  if (MODE == 0) stage_half(Wg, (t + 2) * 64, Bcur, tid);
  FENCE; BAR;
  __builtin_amdgcn_s_setprio(1);
#pragma unroll
  for (int m = 0; m < 4; ++m)
#pragma unroll
    for (int n = 0; n < 2; ++n)
      acc[4 + m][n] = MFMAI8(afr[m], bfr[n], acc[4 + m][n]);
  __builtin_amdgcn_s_setprio(0);
  FENCE; BAR;

  // ---- P4: stage B1(t+2) + A0(t+2); counted vmcnt once per tile
  if (MODE == 0) {
    stage_half(Wg + 128 * KK, (t + 2) * 64, Bcur + 8192, tid);
    stage_half(Ag, (t + 2) * 64, Acur, tid);
    WAITVM(3);
  } else if (MODE == 1) {
    WAITVM(0);
  }
  FENCE; BAR;
  __builtin_amdgcn_s_setprio(1);
#pragma unroll
  for (int m = 0; m < 4; ++m)
#pragma unroll
    for (int n = 0; n < 2; ++n)
      acc[4 + m][2 + n] = MFMAI8(afr[m], bfr[2 + n], acc[4 + m][2 + n]);
  __builtin_amdgcn_s_setprio(0);
  FENCE; BAR;
}

__global__ __launch_bounds__(512, 2) void gemm_k(const u8* __restrict__ A,
                                                 const u8* __restrict__ W,
                                                 const float* __restrict__ dA,
                                                 const float* __restrict__ scales,
                                                 const float* __restrict__ bias,
                                                 float* __restrict__ out) {
  __shared__ u8 sh[65536];  // 64 KiB

  // T1: XCD-aware swizzle (nwg = 256)
  const int cpx = gridDim.x >> 3;
  const int wg = (blockIdx.x & 7) * cpx + (blockIdx.x >> 3);
  const int bm = wg >> 4;
  const int bn = wg & 15;

  const int tid = threadIdx.x;
  const int lane = tid & 63;
  const int lr = lane & 15;
  const int hi = lane >> 4;
  const int wid = tid >> 6;
  const int wr = wid >> 2;  // 2 (M) x 4 (N) wave grid; wave tile 128x64
  const int wc = wid & 3;

  i32x4 acc[8][4] = {};

  const u8* Ag = A + (size_t)bm * 256 * KK;
  const u8* Wg = W + (size_t)bn * 256 * KK;

  // ---- prologue: tile0 all 4 halves + tile1 {B0,B1,A0} (7 gloads/thread)
  stage_half(Wg,             0, BBUF(sh, 0),        tid);
  stage_half(Wg + 128 * KK,  0, BBUF(sh, 0) + 8192, tid);
  stage_half(Ag,             0, ABUF(sh, 0),        tid);
  stage_half(Ag + 128 * KK,  0, ABUF(sh, 0) + 8192, tid);
  stage_half(Wg,            64, BBUF(sh, 1),        tid);
  stage_half(Wg + 128 * KK, 64, BBUF(sh, 1) + 8192, tid);
  stage_half(Ag,            64, ABUF(sh, 1),        tid);
  WAITVM(3);  // tile0 landed; tile1 {B0,B1,A0} in flight
  BAR;

  for (int t = 0; t < 62; ++t)
    do_tile<0>(t, acc, Ag, Wg, sh, tid, lr, hi, wr, wc);
  do_tile<1>(62, acc, Ag, Wg, sh, tid, lr, hi, wr, wc);
  do_tile<2>(63, acc, Ag, Wg, sh, tid, lr, hi, wr, wc);

  // ---- epilogue: dequant (dA[row] * scales[col]) + bias, fp32 store
  // C/D layout: col = lane&15, row = (lane>>4)*4 + reg
  const int colb = bn * 256 + wc * 64 + lr;
  const int rowb0 = bm * 256 + wr * 128 + (hi << 2);
#pragma unroll
  for (int m = 0; m < 8; ++m) {
    const int row = rowb0 + m * 16;
    const float da0 = dA[row], da1 = dA[row + 1], da2 = dA[row + 2], da3 = dA[row + 3];
#pragma unroll
    for (int n = 0; n < 4; ++n) {
      const int col = colb + n * 16;
      const float sc = scales[col];
      const float bi = bias[col];
      out[(size_t)(row + 0) * NN + col] = (float)acc[m][n][0] * (da0 * sc) + bi;
      out[(size_t)(row + 1) * NN + col] = (float)acc[m][n][1] * (da1 * sc) + bi;
      out[(size_t)(row + 2) * NN + col] = (float)acc[m][n][2] * (da2 * sc) + bi;
      out[(size_t)(row + 3) * NN + col] = (float)acc[m][n][3] * (da3 * sc) + bi;
    }
  }
}

// ---- fallback (ws too small): correct but slow -----------------------------
__global__ __launch_bounds__(256) void fb_k(const float* __restrict__ A,
                                            const int* __restrict__ W,
                                            const float* __restrict__ scales,
                                            const float* __restrict__ bias,
                                            float* __restrict__ out) {
  __shared__ float Arow[KK];
  const int m = blockIdx.y;
  const int n0 = blockIdx.x * 256;
  const int tid = threadIdx.x;
  for (int k = tid; k < KK; k += 256) Arow[k] = A[(size_t)m * KK + k];
  __syncthreads();
  const int n = n0 + tid;
  float acc = 0.f;
  const int* wrp = W + (size_t)n * KK;
  for (int k = 0; k < KK; ++k) acc += Arow[k] * (float)wrp[k];
  out[(size_t)m * NN + n] = acc * scales[n] + bias[n];
}

extern "C" void kernel_launch(void* const* d_in, const int* in_sizes, int n_in,
                              void* d_out, int out_size, void* d_ws, size_t ws_size,
                              hipStream_t stream) {
  const float* input = (const float*)d_in[0];
  const int* w8 = (const int*)d_in[1];
  const float* scales = (const float*)d_in[2];
  const float* bias = (const float*)d_in[3];
  float* out = (float*)d_out;

  const size_t nelem = (size_t)NN * KK;                    // 16,777,216
  const size_t need = 2 * nelem + MM * sizeof(float);      // 32 MiB + 16 KiB

  if (ws_size >= need) {
    u8* Wq = (u8*)d_ws;
    u8* Aq = Wq + nelem;
    float* dA = (float*)(Aq + nelem);
    cvt_w_k<<<4096, 256, 0, stream>>>(w8, Wq);             // 16 i8/thread
    cvt_a_k<<<MM, 256, 0, stream>>>(input, Aq, dA);        // 1 row/block
    gemm_k<<<256, 512, 0, stream>>>(Aq, Wq, dA, scales, bias, out);
  } else {
    dim3 grid(NN / 256, MM);
    fb_k<<<grid, 256, 0, stream>>>(input, w8, scales, bias, out);
  }
}

// Round 9
// 97.487 us; speedup vs baseline: 4.3509x; 1.0123x over previous
//
#include <hip/hip_runtime.h>
#include <hip/hip_bf16.h>

typedef unsigned short u16;
typedef unsigned int u32;
typedef unsigned char u8;
typedef __attribute__((ext_vector_type(4))) int i32x4;

#define MM 4096
#define NN 4096
#define KK 4096   // K in elements == bytes for int8

#define BAR __builtin_amdgcn_s_barrier()
#define FENCE asm volatile("" ::: "memory")
#define WAITVM(n) asm volatile("s_waitcnt vmcnt(" #n ")" ::: "memory")

// LDS (bytes): A0 @0, B0 @16384, A1 @32768, B1 @49152; halves +8192
#define ABUF(sh, b) ((sh) + (b) * 32768)
#define BBUF(sh, b) ((sh) + 16384 + (b) * 32768)

// ---- W: int32 -> packed int8 ----------------------------------------------
__global__ __launch_bounds__(256) void cvt_w_k(const int* __restrict__ w,
                                               u8* __restrict__ o) {
  int i = blockIdx.x * 256 + threadIdx.x;     // 16 int8 per thread
  const int4* w4 = (const int4*)w + (size_t)i * 4;
  i32x4 r;
#pragma unroll
  for (int j = 0; j < 4; ++j) {
    int4 v = w4[j];
    r[j] = (v.x & 255) | ((v.y & 255) << 8) | ((v.z & 255) << 16) | ((u32)(v.w & 255) << 24);
  }
  *(i32x4*)(o + (size_t)i * 16) = r;
}

// ---- A: fp32 -> int8 with per-row symmetric scale (one block per row) ------
__global__ __launch_bounds__(256) void cvt_a_k(const float* __restrict__ x,
                                               u8* __restrict__ o,
                                               float* __restrict__ dA) {
  const int row = blockIdx.x;
  const float4* xr = (const float4*)(x + (size_t)row * KK);
  const int t = threadIdx.x;
  float4 v[4];
  float mx = 0.f;
#pragma unroll
  for (int j = 0; j < 4; ++j) {
    v[j] = xr[t + j * 256];
    mx = fmaxf(mx, fmaxf(fmaxf(fabsf(v[j].x), fabsf(v[j].y)),
                         fmaxf(fabsf(v[j].z), fabsf(v[j].w))));
  }
#pragma unroll
  for (int off = 32; off; off >>= 1) mx = fmaxf(mx, __shfl_down(mx, off));
  __shared__ float sm[4];
  if ((t & 63) == 0) sm[t >> 6] = mx;
  __syncthreads();
  mx = fmaxf(fmaxf(sm[0], sm[1]), fmaxf(sm[2], sm[3]));
  mx = fmaxf(mx, 1e-20f);
  const float inv = 127.0f / mx;
  if (t == 0) dA[row] = mx / 127.0f;
  u32* orow = (u32*)(o + (size_t)row * KK);
#pragma unroll
  for (int j = 0; j < 4; ++j) {
    int qx = (int)rintf(v[j].x * inv), qy = (int)rintf(v[j].y * inv);
    int qz = (int)rintf(v[j].z * inv), qw = (int)rintf(v[j].w * inv);
    orow[t + j * 256] =
        (qx & 255) | ((qy & 255) << 8) | ((qz & 255) << 16) | ((u32)(qw & 255) << 24);
  }
}

// ---- async global->LDS, width 16 ------------------------------------------
__device__ __forceinline__ void gload16(const u8* g, u8* l) {
  __builtin_amdgcn_global_load_lds(
      (const __attribute__((address_space(1))) void*)g,
      (__attribute__((address_space(3))) void*)l, 16, 0, 0);
}

// Stage one half-tile (128 rows x 64 B) = 8 KB; ONE gload16 per thread.
// LDS dest linear; swizzle via permuted global source chunk.
__device__ __forceinline__ void stage_half(const u8* __restrict__ gRowBase,
                                           int k0, u8* ldsHalf, int tid) {
  int row = tid >> 2;                        // 4 x16B chunks per 64B row
  int c = (tid & 3) ^ ((row >> 1) & 3);
  gload16(gRowBase + (size_t)row * KK + k0 + c * 16, ldsHalf + tid * 16);
}

// Swizzled read of one 16B i8 fragment at logical (row r, 16B-chunk q).
__device__ __forceinline__ i32x4 ldsfrag(const u8* base, int r, int q) {
  return *(const i32x4*)(base + r * 64 + (((q ^ (r >> 1)) & 3) << 4));
}

#define MFMAI8(a, b, c) __builtin_amdgcn_mfma_i32_16x16x64_i8(a, b, c, 0, 0, 0)

// ---- 256x256 tile, BK=64, 4 regions/tile, reads pipelined INTO MFMA regions.
// Region k's ds_reads feed region k+1's MFMA -> they drain under this
// region's MFMA cluster (the m201 overlap mechanism, at phase granularity).
// Reads:  R1: bfr23(t) | R2: afr1(t) | R3: afr0(t+1) | R4: bfr01(t+1)
// Stages: R2: B0,B1(t+2) | R3: A0,A1(t+2)
// Wait:   single WAITVM(2) at R2 end (drains A(t+1), staged 3 regions prior),
//         BAR before any dependent read. Tails: MODE1 WAITVM(0); MODE2 none.
template <int MODE>  // 0 = steady (t<=61), 1 = t==62, 2 = t==63
__device__ __forceinline__ void do_tile(
    int t, i32x4 (&acc)[8][4], const u8* Ag, const u8* Wg, u8* sh,
    int tid, int lr, int hi, int wr, int wc,
    i32x4 (&afr0)[4], i32x4 (&afr1)[4], i32x4 (&bfr01)[2], i32x4 (&bfr23)[2]) {
  const int b = t & 1;
  u8* Acur = ABUF(sh, b);
  u8* Anxt = ABUF(sh, b ^ 1);
  u8* Bcur = BBUF(sh, b);
  u8* Bnxt = BBUF(sh, b ^ 1);

  // ---- R1: read bfr23(t); MFMA P1 = afr0 x bfr01
#pragma unroll
  for (int n = 0; n < 2; ++n)
    bfr23[n] = ldsfrag(Bcur, wc * 64 + (2 + n) * 16 + lr, hi);
  __builtin_amdgcn_s_setprio(1);
#pragma unroll
  for (int m = 0; m < 4; ++m)
#pragma unroll
    for (int n = 0; n < 2; ++n)
      acc[m][n] = MFMAI8(afr0[m], bfr01[n], acc[m][n]);
  __builtin_amdgcn_s_setprio(0);
  FENCE; BAR;

  // ---- R2: read afr1(t); stage B0,B1(t+2); MFMA P2 = afr0 x bfr23; WAITVM
#pragma unroll
  for (int m = 0; m < 4; ++m)
    afr1[m] = ldsfrag(Acur, wr * 128 + 64 + m * 16 + lr, hi);
  if (MODE == 0) {
    stage_half(Wg,            (t + 2) * 64, Bcur,        tid);
    stage_half(Wg + 128 * KK, (t + 2) * 64, Bcur + 8192, tid);
  }
  __builtin_amdgcn_s_setprio(1);
#pragma unroll
  for (int m = 0; m < 4; ++m)
#pragma unroll
    for (int n = 0; n < 2; ++n)
      acc[m][2 + n] = MFMAI8(afr0[m], bfr23[n], acc[m][2 + n]);
  __builtin_amdgcn_s_setprio(0);
  if (MODE == 0) { WAITVM(2); } else if (MODE == 1) { WAITVM(0); }
  FENCE; BAR;

  // ---- R3: read afr0(t+1); stage A0,A1(t+2); MFMA P3 = afr1 x bfr01
  if (MODE <= 1) {
#pragma unroll
    for (int m = 0; m < 4; ++m)
      afr0[m] = ldsfrag(Anxt, wr * 128 + m * 16 + lr, hi);
  }
  if (MODE == 0) {
    stage_half(Ag,            (t + 2) * 64, Acur,        tid);
    stage_half(Ag + 128 * KK, (t + 2) * 64, Acur + 8192, tid);
  }
  __builtin_amdgcn_s_setprio(1);
#pragma unroll
  for (int m = 0; m < 4; ++m)
#pragma unroll
    for (int n = 0; n < 2; ++n)
      acc[4 + m][n] = MFMAI8(afr1[m], bfr01[n], acc[4 + m][n]);
  __builtin_amdgcn_s_setprio(0);
  FENCE; BAR;

  // ---- R4: read bfr01(t+1); MFMA P4 = afr1 x bfr23
  if (MODE <= 1) {
#pragma unroll
    for (int n = 0; n < 2; ++n)
      bfr01[n] = ldsfrag(Bnxt, wc * 64 + n * 16 + lr, hi);
  }
  __builtin_amdgcn_s_setprio(1);
#pragma unroll
  for (int m = 0; m < 4; ++m)
#pragma unroll
    for (int n = 0; n < 2; ++n)
      acc[4 + m][2 + n] = MFMAI8(afr1[m], bfr23[n], acc[4 + m][2 + n]);
  __builtin_amdgcn_s_setprio(0);
  FENCE; BAR;
}

__global__ __launch_bounds__(512, 2) void gemm_k(const u8* __restrict__ A,
                                                 const u8* __restrict__ W,
                                                 const float* __restrict__ dA,
                                                 const float* __restrict__ scales,
                                                 const float* __restrict__ bias,
                                                 float* __restrict__ out) {
  __shared__ u8 sh[65536];  // 64 KiB

  // T1: XCD-aware swizzle (nwg = 256)
  const int cpx = gridDim.x >> 3;
  const int wg = (blockIdx.x & 7) * cpx + (blockIdx.x >> 3);
  const int bm = wg >> 4;
  const int bn = wg & 15;

  const int tid = threadIdx.x;
  const int lane = tid & 63;
  const int lr = lane & 15;
  const int hi = lane >> 4;
  const int wid = tid >> 6;
  const int wr = wid >> 2;  // 2 (M) x 4 (N) wave grid; wave tile 128x64
  const int wc = wid & 3;

  i32x4 acc[8][4] = {};
  i32x4 afr0[4], afr1[4], bfr01[2], bfr23[2];

  const u8* Ag = A + (size_t)bm * 256 * KK;
  const u8* Wg = W + (size_t)bn * 256 * KK;

  // ---- prologue: tile0 all 4 halves + tile1 all 4 halves (8 gloads/thread)
  stage_half(Wg,             0, BBUF(sh, 0),        tid);  // B0(0)
  stage_half(Wg + 128 * KK,  0, BBUF(sh, 0) + 8192, tid);  // B1(0)
  stage_half(Ag,             0, ABUF(sh, 0),        tid);  // A0(0)
  stage_half(Ag + 128 * KK,  0, ABUF(sh, 0) + 8192, tid);  // A1(0)
  stage_half(Wg,            64, BBUF(sh, 1),        tid);  // B0(1)
  stage_half(Wg + 128 * KK, 64, BBUF(sh, 1) + 8192, tid);  // B1(1)
  stage_half(Ag,            64, ABUF(sh, 1),        tid);  // A0(1)
  stage_half(Ag + 128 * KK, 64, ABUF(sh, 1) + 8192, tid);  // A1(1)
  WAITVM(4);  // tile0's 4 halves landed; tile1's 4 may be in flight
  BAR;
  // prefetch operands for R1(0)
#pragma unroll
  for (int m = 0; m < 4; ++m)
    afr0[m] = ldsfrag(ABUF(sh, 0), wr * 128 + m * 16 + lr, hi);
#pragma unroll
  for (int n = 0; n < 2; ++n)
    bfr01[n] = ldsfrag(BBUF(sh, 0), wc * 64 + n * 16 + lr, hi);

  for (int t = 0; t < 62; ++t)
    do_tile<0>(t, acc, Ag, Wg, sh, tid, lr, hi, wr, wc, afr0, afr1, bfr01, bfr23);
  do_tile<1>(62, acc, Ag, Wg, sh, tid, lr, hi, wr, wc, afr0, afr1, bfr01, bfr23);
  do_tile<2>(63, acc, Ag, Wg, sh, tid, lr, hi, wr, wc, afr0, afr1, bfr01, bfr23);

  // ---- epilogue: dequant (dA[row] * scales[col]) + bias, fp32 store
  // C/D layout: col = lane&15, row = (lane>>4)*4 + reg
  const int colb = bn * 256 + wc * 64 + lr;
  const int rowb0 = bm * 256 + wr * 128 + (hi << 2);
#pragma unroll
  for (int m = 0; m < 8; ++m) {
    const int row = rowb0 + m * 16;
    const float da0 = dA[row], da1 = dA[row + 1], da2 = dA[row + 2], da3 = dA[row + 3];
#pragma unroll
    for (int n = 0; n < 4; ++n) {
      const int col = colb + n * 16;
      const float sc = scales[col];
      const float bi = bias[col];
      out[(size_t)(row + 0) * NN + col] = (float)acc[m][n][0] * (da0 * sc) + bi;
      out[(size_t)(row + 1) * NN + col] = (float)acc[m][n][1] * (da1 * sc) + bi;
      out[(size_t)(row + 2) * NN + col] = (float)acc[m][n][2] * (da2 * sc) + bi;
      out[(size_t)(row + 3) * NN + col] = (float)acc[m][n][3] * (da3 * sc) + bi;
    }
  }
}

// ---- fallback (ws too small): correct but slow -----------------------------
__global__ __launch_bounds__(256) void fb_k(const float* __restrict__ A,
                                            const int* __restrict__ W,
                                            const float* __restrict__ scales,
                                            const float* __restrict__ bias,
                                            float* __restrict__ out) {
  __shared__ float Arow[KK];
  const int m = blockIdx.y;
  const int n0 = blockIdx.x * 256;
  const int tid = threadIdx.x;
  for (int k = tid; k < KK; k += 256) Arow[k] = A[(size_t)m * KK + k];
  __syncthreads();
  const int n = n0 + tid;
  float acc = 0.f;
  const int* wrp = W + (size_t)n * KK;
  for (int k = 0; k < KK; ++k) acc += Arow[k] * (float)wrp[k];
  out[(size_t)m * NN + n] = acc * scales[n] + bias[n];
}

extern "C" void kernel_launch(void* const* d_in, const int* in_sizes, int n_in,
                              void* d_out, int out_size, void* d_ws, size_t ws_size,
                              hipStream_t stream) {
  const float* input = (const float*)d_in[0];
  const int* w8 = (const int*)d_in[1];
  const float* scales = (const float*)d_in[2];
  const float* bias = (const float*)d_in[3];
  float* out = (float*)d_out;

  const size_t nelem = (size_t)NN * KK;                    // 16,777,216
  const size_t need = 2 * nelem + MM * sizeof(float);      // 32 MiB + 16 KiB

  if (ws_size >= need) {
    u8* Wq = (u8*)d_ws;
    u8* Aq = Wq + nelem;
    float* dA = (float*)(Aq + nelem);
    cvt_w_k<<<4096, 256, 0, stream>>>(w8, Wq);             // 16 i8/thread
    cvt_a_k<<<MM, 256, 0, stream>>>(input, Aq, dA);        // 1 row/block
    gemm_k<<<256, 512, 0, stream>>>(Aq, Wq, dA, scales, bias, out);
  } else {
    dim3 grid(NN / 256, MM);
    fb_k<<<grid, 256, 0, stream>>>(input, w8, scales, bias, out);
  }
}